// Round 4
// baseline (338.215 us; speedup 1.0000x reference)
//
#include <hip/hip_runtime.h>

#define NSTEP 365
#define NGRID 50000
#define PRECS_F 1e-5f
#define CHUNK 16
#define NCHUNK ((NSTEP + CHUNK - 1) / CHUNK)   // 23

#if defined(__has_builtin)
#  if __has_builtin(__builtin_amdgcn_exp2f) && __has_builtin(__builtin_amdgcn_logf)
#    define FAST_EXP2(v) __builtin_amdgcn_exp2f(v)
#    define FAST_LOG2(v) __builtin_amdgcn_logf(v)
#  endif
#endif
#ifndef FAST_EXP2
#  define FAST_EXP2(v) exp2f(v)
#  define FAST_LOG2(v) log2f(v)
#endif

// s_waitcnt simm16 (gfx9): vmcnt[3:0]=bits[3:0], vmcnt[5:4]=bits[15:14],
// expcnt=bits[6:4], lgkmcnt=bits[11:8]. "no wait" fields = all-ones.
#define WAITCNT_VM48 0xCF70   // vmcnt(48), expcnt/lgkmcnt don't-care
#define WAITCNT_VM0  0x0F70   // vmcnt(0)

typedef const void __attribute__((address_space(1)))* gas_cptr;
typedef void __attribute__((address_space(3)))*       las_ptr;

__global__ __launch_bounds__(64) void hbv_kernel(const float* __restrict__ x,
                                                 const float* __restrict__ params,
                                                 float* __restrict__ out) {
    // Double-buffered LDS: [buf][step-in-chunk][component][lane]. 24.6 KB.
    // Filled by size=4 global_load_lds DMA (lane-stride 4 B, m03-verified).
    __shared__ float lds[2][CHUNK][3][64];

    const int lane = threadIdx.x;                    // 0..63
    const int g    = blockIdx.x * 64 + lane;         // cell this lane owns
    const int gg   = (g < NGRID) ? g : (NGRID - 1);  // clamped for loads

    // ---- scale parameters: p = lo + raw * (hi - lo) ----
    const float* pr = params + (size_t)gg * 14;
    const float parBETA  = 1.0f   + pr[0]  * 5.0f;
    const float parFC    = 50.0f  + pr[1]  * 950.0f;
    const float parK0    = 0.05f  + pr[2]  * 0.85f;
    const float parK1    = 0.01f  + pr[3]  * 0.49f;
    const float parK2    = 0.001f + pr[4]  * 0.199f;
    const float parLP    = 0.2f   + pr[5]  * 0.8f;
    const float parPERC  =          pr[6]  * 10.0f;
    const float parUZL   =          pr[7]  * 100.0f;
    const float parTT    = -2.5f  + pr[8]  * 5.0f;
    const float parCFMAX = 0.5f   + pr[9]  * 9.5f;
    const float parCFR   =          pr[10] * 0.1f;
    const float parCWH   =          pr[11] * 0.2f;

    const float invFC     = 1.0f / parFC;
    const float invLPFC   = 1.0f / (parLP * parFC);
    const float cfr_cfmax = parCFR * parCFMAX;

    float SNOWPACK = 0.001f, MELTWATER = 0.001f, SM = 0.001f, SUZ = 0.001f, SLZ = 0.001f;

    // 48 size=4 DMAs per chunk: component k of step j lands at
    // lds[b][j][k][lane] (HW: wave-uniform LDS base + lane*4).
    auto stage = [&](int cidx) {
        const int b     = cidx & 1;
        const int tbase = cidx * CHUNK;
        #pragma unroll
        for (int j = 0; j < CHUNK; ++j) {
            int t = tbase + j;
            t = (t < NSTEP) ? t : (NSTEP - 1);           // clamp (tail chunk)
            const float* gp = x + ((size_t)t * NGRID + gg) * 3;
            __builtin_amdgcn_global_load_lds((gas_cptr)(gp + 0), (las_ptr)&lds[b][j][0][0], 4, 0, 0);
            __builtin_amdgcn_global_load_lds((gas_cptr)(gp + 1), (las_ptr)&lds[b][j][1][0], 4, 0, 0);
            __builtin_amdgcn_global_load_lds((gas_cptr)(gp + 2), (las_ptr)&lds[b][j][2][0], 4, 0, 0);
        }
    };

    auto compute = [&](int cidx) {
        const int b  = cidx & 1;
        const int t0 = cidx * CHUNK;
        #pragma unroll
        for (int j = 0; j < CHUNK; ++j) {
            const float PRECIP = lds[b][j][0][lane];
            const float Tt     = lds[b][j][1][lane];
            const float ETp    = lds[b][j][2][lane];

            float RAIN = (Tt >= parTT) ? PRECIP : 0.0f;
            float SNOW = PRECIP - RAIN;
            SNOWPACK += SNOW;
            float melt = fminf(fmaxf(parCFMAX * (Tt - parTT), 0.0f), SNOWPACK);
            MELTWATER += melt;
            SNOWPACK  -= melt;
            float refreeze = fminf(fmaxf(cfr_cfmax * (parTT - Tt), 0.0f), MELTWATER);
            SNOWPACK  += refreeze;
            MELTWATER -= refreeze;
            float tosoil = fmaxf(MELTWATER - parCWH * SNOWPACK, 0.0f);
            MELTWATER -= tosoil;

            float ratio = SM * invFC;                    // SM in (0, FC] -> (0,1]
            float sw = FAST_EXP2(parBETA * FAST_LOG2(ratio));
            sw = fminf(fmaxf(sw, 0.0f), 1.0f);
            float recharge = (RAIN + tosoil) * sw;
            SM += RAIN + tosoil - recharge;
            float excess = fmaxf(SM - parFC, 0.0f);
            SM -= excess;
            float evapfactor = fminf(fmaxf(SM * invLPFC, 0.0f), 1.0f);
            float ETact = fminf(SM, ETp * evapfactor);
            SM = fmaxf(SM - ETact, PRECS_F);

            SUZ += recharge + excess;
            float PERC = fminf(SUZ, parPERC);
            SUZ -= PERC;
            float Q0 = parK0 * fmaxf(SUZ - parUZL, 0.0f);
            SUZ -= Q0;
            float Q1 = parK1 * SUZ;
            SUZ -= Q1;
            SLZ += PERC;
            float Q2 = parK2 * SLZ;
            SLZ -= Q2;

            const int t = t0 + j;
            if (t < NSTEP && g < NGRID)
                out[(size_t)t * NGRID + g] = Q0 + Q1 + Q2;
        }
    };

    // Software pipeline (single wave per block -> no barrier; explicit vmcnt).
    // After stage(c+1), >=48 VMEM ops were issued after chunk c's DMAs, so
    // vmcnt(48) guarantees chunk c landed while chunk c+1 stays in flight.
    stage(0);
    for (int c = 0; c < NCHUNK; ++c) {
        if (c + 1 < NCHUNK) {
            stage(c + 1);
            __builtin_amdgcn_s_waitcnt(WAITCNT_VM48);
        } else {
            __builtin_amdgcn_s_waitcnt(WAITCNT_VM0);   // last chunk: full drain
        }
        asm volatile("" ::: "memory");   // keep ds_reads below the wait
        compute(c);
    }
}

extern "C" void kernel_launch(void* const* d_in, const int* in_sizes, int n_in,
                              void* d_out, int out_size, void* d_ws, size_t ws_size,
                              hipStream_t stream) {
    const float* x      = (const float*)d_in[0];
    const float* params = (const float*)d_in[1];
    float* out          = (float*)d_out;

    const int block = 64;                              // 1 wave per block
    const int grid  = (NGRID + block - 1) / block;     // 782 blocks over 256 CUs
    hbv_kernel<<<grid, block, 0, stream>>>(x, params, out);
}